// Round 6
// baseline (292.516 us; speedup 1.0000x reference)
//
#include <hip/hip_runtime.h>

#define N_NODES 20000
#define N_EDGES 400000
#define NODE_DIM 256
#define HIDDEN 256
#define OUT_DIM 128
#define PROJ_BLOCKS 628  // 157 m-blocks * 4 n-blocks
#define CONV_BLOCKS 256

typedef __attribute__((ext_vector_type(8))) short short8;
typedef __attribute__((ext_vector_type(4))) float f32x4;

__device__ inline unsigned short f2bf(float f) {
  union { float f; unsigned u; } v; v.f = f;
  unsigned r = (v.u + 0x7FFFu + ((v.u >> 16) & 1u)) >> 16;
  return (unsigned short)r;
}

// ---------------- Kernel 1: bf16 MFMA proj GEMM + attrs->bf16 convert.
// C layout (bf16): C[node][half*256 + nbase + c*4 + t] where h = nbase + t*16 + c.
// half 0 = x@W_src, half 1 = x@W_dst + b_edge (bias folded here).
__global__ __launch_bounds__(256) void proj_mfma(
    const float* __restrict__ x, const float* __restrict__ We,
    const float* __restrict__ be, unsigned short* __restrict__ C,
    float* __restrict__ partial, const float* __restrict__ attrs,
    unsigned short* __restrict__ attrs_bf) {
  const int tid = threadIdx.x;
  if (blockIdx.x >= PROJ_BLOCKS) {
    // convert attrs fp32 -> bf16
    const int nt = CONV_BLOCKS * 256;
    const int total4 = 4 * N_EDGES * 16 / 4;
    for (int i = (blockIdx.x - PROJ_BLOCKS) * 256 + tid; i < total4; i += nt) {
      float4 v = ((const float4*)attrs)[i];
      ushort4 o;
      o.x = f2bf(v.x); o.y = f2bf(v.y); o.z = f2bf(v.z); o.w = f2bf(v.w);
      ((ushort4*)attrs_bf)[i] = o;
    }
    return;
  }
  if (blockIdx.x == 0) {
    for (int i = tid; i < 4 * HIDDEN; i += 256) partial[i] = 0.f;
  }
  const int bm = blockIdx.x >> 2;
  const int bn = blockIdx.x & 3;
  const int row0 = bm * 128;
  const int col0 = bn * 128;          // 0,128,256,384
  const int half = col0 >> 8;         // 0: W_src, 1: W_dst
  const int ncol0 = col0 & 255;       // 0 or 128 within half
  const int lane = tid & 63, wave = tid >> 6;
  const int q = lane >> 4, c = lane & 15;
  const int wm = wave >> 1, wn = wave & 1;

  // row stride 40 ushorts = 80 B: b128 fragment reads spread over all banks (2-way, free)
  __shared__ unsigned short As[128][40];  // [m][k]
  __shared__ unsigned short Bs[128][40];  // [n][k] (transposed W)

  f32x4 acc[4][4];
#pragma unroll
  for (int i = 0; i < 4; ++i)
#pragma unroll
    for (int t = 0; t < 4; ++t) acc[i][t] = (f32x4){0.f, 0.f, 0.f, 0.f};

  const int ar = tid >> 1;            // A stage row 0..127
  const int ak = (tid & 1) * 16;      // A stage k 0/16
  const int bk = tid >> 3;            // B stage k 0..31
  const int bn0 = (tid & 7) * 16;     // B stage n 0..112

  for (int k0 = 0; k0 < NODE_DIM; k0 += 32) {
    {  // A: x rows -> bf16 LDS
      const int r = row0 + ar;
      short8 t0, t1;
      if (r < N_NODES) {
        const float4* src = (const float4*)&x[(size_t)r * NODE_DIM + k0 + ak];
        float4 f0 = src[0], f1 = src[1], f2 = src[2], f3 = src[3];
        t0[0]=f2bf(f0.x); t0[1]=f2bf(f0.y); t0[2]=f2bf(f0.z); t0[3]=f2bf(f0.w);
        t0[4]=f2bf(f1.x); t0[5]=f2bf(f1.y); t0[6]=f2bf(f1.z); t0[7]=f2bf(f1.w);
        t1[0]=f2bf(f2.x); t1[1]=f2bf(f2.y); t1[2]=f2bf(f2.z); t1[3]=f2bf(f2.w);
        t1[4]=f2bf(f3.x); t1[5]=f2bf(f3.y); t1[6]=f2bf(f3.z); t1[7]=f2bf(f3.w);
      } else {
#pragma unroll
        for (int j = 0; j < 8; ++j) { t0[j] = 0; t1[j] = 0; }
      }
      *(short8*)&As[ar][ak] = t0;
      *(short8*)&As[ar][ak + 8] = t1;
    }
    {  // B: We rows -> transposed bf16 LDS
      const float4* src = (const float4*)&We[(size_t)(half * 256 + k0 + bk) * HIDDEN + ncol0 + bn0];
#pragma unroll
      for (int v = 0; v < 4; ++v) {
        float4 f = src[v];
        Bs[bn0 + v * 4 + 0][bk] = f2bf(f.x);
        Bs[bn0 + v * 4 + 1][bk] = f2bf(f.y);
        Bs[bn0 + v * 4 + 2][bk] = f2bf(f.z);
        Bs[bn0 + v * 4 + 3][bk] = f2bf(f.w);
      }
    }
    __syncthreads();
    short8 Af[4], Bf[4];
#pragma unroll
    for (int i = 0; i < 4; ++i) Af[i] = *(const short8*)&As[wm * 64 + i * 16 + c][q * 8];
#pragma unroll
    for (int t = 0; t < 4; ++t) Bf[t] = *(const short8*)&Bs[wn * 64 + t * 16 + c][q * 8];
#pragma unroll
    for (int i = 0; i < 4; ++i)
#pragma unroll
      for (int t = 0; t < 4; ++t)
        acc[i][t] = __builtin_amdgcn_mfma_f32_16x16x32_bf16(Af[i], Bf[t], acc[i][t], 0, 0, 0);
    __syncthreads();
  }

  float biasv[4] = {0.f, 0.f, 0.f, 0.f};
  const int nbase = ncol0 + wn * 64;
  if (half) {
#pragma unroll
    for (int t = 0; t < 4; ++t) biasv[t] = be[nbase + t * 16 + c];
  }
#pragma unroll
  for (int i = 0; i < 4; ++i) {
#pragma unroll
    for (int r = 0; r < 4; ++r) {
      const int node = row0 + wm * 64 + i * 16 + q * 4 + r;
      if (node < N_NODES) {
        ushort4 o;
        o.x = f2bf(acc[i][0][r] + biasv[0]);
        o.y = f2bf(acc[i][1][r] + biasv[1]);
        o.z = f2bf(acc[i][2][r] + biasv[2]);
        o.w = f2bf(acc[i][3][r] + biasv[3]);
        *(ushort4*)&C[(size_t)node * 512 + half * 256 + nbase + c * 4] = o;
      }
    }
  }
}

// ---------------- Kernel 2: MFMA fused gather + attr-GEMM + relu + mean.
// Base gather from permuted bf16 C; base folded into MFMA accumulator (D=A*B+C).
template <bool PRE>
__global__ __launch_bounds__(256) void edge_mfma(
    const unsigned short* __restrict__ C, const int* __restrict__ ei,
    const float* __restrict__ attrs_f, const unsigned short* __restrict__ attrs_b,
    const float* __restrict__ We, float* __restrict__ partial) {
  const int tid = threadIdx.x;
  const int lane = tid & 63, wave = tid >> 6;
  const int q = lane >> 4, c = lane & 15;
  const int hb = wave * 64;

  short8 Bf[4];
#pragma unroll
  for (int t = 0; t < 4; ++t) {
    short8 bf;
#pragma unroll
    for (int j = 0; j < 8; ++j) {
      int k = q * 8 + j;
      float w = (k < 16) ? We[(size_t)(512 + k) * HIDDEN + hb + t * 16 + c] : 0.0f;
      bf[j] = (short)f2bf(w);
    }
    Bf[t] = bf;
  }

  f32x4 acc4[4][4];  // [b][t]
#pragma unroll
  for (int b = 0; b < 4; ++b)
#pragma unroll
    for (int t = 0; t < 4; ++t) acc4[b][t] = (f32x4){0.f, 0.f, 0.f, 0.f};

  const int ngroups = N_EDGES / 16;
  for (int g = blockIdx.x; g < ngroups; g += gridDim.x) {
    const int e0 = g * 16;
    const int4 ns4 = *(const int4*)&ei[e0 + q * 4];
    const int4 nd4 = *(const int4*)&ei[N_EDGES + e0 + q * 4];

    short8 Af[4];
    if (PRE) {
      if (q < 2) {
#pragma unroll
        for (int b = 0; b < 4; ++b)
          Af[b] = *(const short8*)&attrs_b[((size_t)b * N_EDGES + e0 + c) * 16 + q * 8];
      } else {
        short8 z;
#pragma unroll
        for (int j = 0; j < 8; ++j) z[j] = 0;
#pragma unroll
        for (int b = 0; b < 4; ++b) Af[b] = z;
      }
    } else {
      if (q < 2) {
#pragma unroll
        for (int b = 0; b < 4; ++b) {
          const size_t off = ((size_t)b * N_EDGES + e0 + c) * 16 + q * 8;
          const float4 a0 = *(const float4*)&attrs_f[off];
          const float4 a1 = *(const float4*)&attrs_f[off + 4];
          short8 af;
          af[0]=f2bf(a0.x); af[1]=f2bf(a0.y); af[2]=f2bf(a0.z); af[3]=f2bf(a0.w);
          af[4]=f2bf(a1.x); af[5]=f2bf(a1.y); af[6]=f2bf(a1.z); af[7]=f2bf(a1.w);
          Af[b] = af;
        }
      } else {
        short8 z;
#pragma unroll
        for (int j = 0; j < 8; ++j) z[j] = 0;
#pragma unroll
        for (int b = 0; b < 4; ++b) Af[b] = z;
      }
    }

    f32x4 base4[4];  // [t], component = row r (bias already folded into dst half)
    {
      const int nn[4] = {ns4.x, ns4.y, ns4.z, ns4.w};
      const int dd[4] = {nd4.x, nd4.y, nd4.z, nd4.w};
#pragma unroll
      for (int r = 0; r < 4; ++r) {
        const uint2 s = *(const uint2*)&C[(size_t)nn[r] * 512 + hb + c * 4];
        const uint2 d = *(const uint2*)&C[(size_t)dd[r] * 512 + 256 + hb + c * 4];
        base4[0][r] = __uint_as_float(s.x << 16) + __uint_as_float(d.x << 16);
        base4[1][r] = __uint_as_float(s.x & 0xFFFF0000u) + __uint_as_float(d.x & 0xFFFF0000u);
        base4[2][r] = __uint_as_float(s.y << 16) + __uint_as_float(d.y << 16);
        base4[3][r] = __uint_as_float(s.y & 0xFFFF0000u) + __uint_as_float(d.y & 0xFFFF0000u);
      }
    }

#pragma unroll
    for (int b = 0; b < 4; ++b) {
#pragma unroll
      for (int t = 0; t < 4; ++t) {
        // D = attrs*Wattr + base, relu, accumulate
        f32x4 u = __builtin_amdgcn_mfma_f32_16x16x32_bf16(Af[b], Bf[t], base4[t], 0, 0, 0);
        u[0] = fmaxf(u[0], 0.f); u[1] = fmaxf(u[1], 0.f);
        u[2] = fmaxf(u[2], 0.f); u[3] = fmaxf(u[3], 0.f);
        acc4[b][t] += u;
      }
    }
  }

#pragma unroll
  for (int b = 0; b < 4; ++b)
#pragma unroll
    for (int t = 0; t < 4; ++t) {
      float v = acc4[b][t][0] + acc4[b][t][1] + acc4[b][t][2] + acc4[b][t][3];
      v += __shfl_xor(v, 16, 64);
      v += __shfl_xor(v, 32, 64);
      if (q == 0) atomicAdd(&partial[b * HIDDEN + hb + t * 16 + c], v);
    }
}

// ---------------- Kernel 3: out[b,o] = (S[b,:]/E) @ W_graph + b_graph
__global__ __launch_bounds__(256) void graph_out(
    const float* __restrict__ partial, const float* __restrict__ Wg,
    const float* __restrict__ bg, float* __restrict__ out) {
  const int o = blockIdx.x;    // 0..127
  const int hh = threadIdx.x;  // 0..255
  const int lane = hh & 63, wave = hh >> 6;
  const float w = Wg[(size_t)hh * OUT_DIM + o];
  float v[4];
#pragma unroll
  for (int b = 0; b < 4; ++b) v[b] = partial[b * HIDDEN + hh] * w;
#pragma unroll
  for (int off = 32; off >= 1; off >>= 1)
#pragma unroll
    for (int b = 0; b < 4; ++b) v[b] += __shfl_down(v[b], off, 64);
  __shared__ float red[4][4];
  if (lane == 0)
#pragma unroll
    for (int b = 0; b < 4; ++b) red[wave][b] = v[b];
  __syncthreads();
  if (hh < 4) {
    float s = red[0][hh] + red[1][hh] + red[2][hh] + red[3][hh];
    out[hh * OUT_DIM + o] = s * (1.0f / (float)N_EDGES) + bg[o];
  }
}

extern "C" void kernel_launch(void* const* d_in, const int* in_sizes, int n_in,
                              void* d_out, int out_size, void* d_ws, size_t ws_size,
                              hipStream_t stream) {
  const float* x  = (const float*)d_in[0];
  const int*   ei = (const int*)d_in[1];
  const float* ea = (const float*)d_in[2];
  const float* We = (const float*)d_in[3];
  const float* be = (const float*)d_in[4];
  const float* Wg = (const float*)d_in[5];
  const float* bg = (const float*)d_in[6];
  float* out = (float*)d_out;

  const size_t C_bytes = (size_t)N_NODES * 512 * 2;         // 20.48 MB
  const size_t A_bytes = (size_t)4 * N_EDGES * 16 * 2;      // 51.2 MB
  unsigned short* C = (unsigned short*)d_ws;
  const bool pre = ws_size >= C_bytes + A_bytes + 4096;
  unsigned short* attrs_bf = pre ? (unsigned short*)((char*)d_ws + C_bytes) : nullptr;
  float* partial = (float*)((char*)d_ws + (pre ? C_bytes + A_bytes : C_bytes));

  const int grid1 = pre ? PROJ_BLOCKS + CONV_BLOCKS : PROJ_BLOCKS;
  proj_mfma<<<grid1, 256, 0, stream>>>(x, We, be, C, partial, ea, attrs_bf);
  if (pre)
    edge_mfma<true><<<2500, 256, 0, stream>>>(C, ei, nullptr, attrs_bf, We, partial);
  else
    edge_mfma<false><<<2500, 256, 0, stream>>>(C, ei, ea, nullptr, We, partial);
  graph_out<<<128, 256, 0, stream>>>(partial, Wg, bg, out);
}

// Round 7
// 291.302 us; speedup vs baseline: 1.0042x; 1.0042x over previous
//
#include <hip/hip_runtime.h>
#include <hip/hip_bf16.h>

#define N_NODES 20000
#define N_EDGES 400000
#define NODE_DIM 256
#define HIDDEN 256
#define OUT_DIM 128
#define PROJ_BLOCKS 628  // 157 m-blocks * 4 n-blocks

typedef __attribute__((ext_vector_type(8))) short short8;
typedef __attribute__((ext_vector_type(4))) float f32x4;

// hardware v_cvt_pk_bf16_f32 (RNE), 2 floats -> packed 2 bf16
__device__ inline unsigned f2bf_pk(float a, float b) {
  __hip_bfloat162 h = __float22bfloat162_rn(float2{a, b});
  union { __hip_bfloat162 h; unsigned u; } v;
  v.h = h;
  return v.u;
}
__device__ inline unsigned short f2bf(float f) {
  union { float f; unsigned u; } v; v.f = f;
  unsigned r = (v.u + 0x7FFFu + ((v.u >> 16) & 1u)) >> 16;
  return (unsigned short)r;
}

// ---------------- Kernel 1: bf16 MFMA proj GEMM.
// C layout (bf16): C[node][half*256 + nbase + c*4 + t] where h = nbase + t*16 + c.
// half 0 = x@W_src, half 1 = x@W_dst + b_edge (bias folded here).
__global__ __launch_bounds__(256) void proj_mfma(
    const float* __restrict__ x, const float* __restrict__ We,
    const float* __restrict__ be, unsigned short* __restrict__ C,
    float* __restrict__ partial) {
  const int tid = threadIdx.x;
  if (blockIdx.x == 0) {
    for (int i = tid; i < 4 * HIDDEN; i += 256) partial[i] = 0.f;
  }
  const int bm = blockIdx.x >> 2;
  const int bn = blockIdx.x & 3;
  const int row0 = bm * 128;
  const int col0 = bn * 128;          // 0,128,256,384
  const int half = col0 >> 8;         // 0: W_src, 1: W_dst
  const int ncol0 = col0 & 255;       // 0 or 128 within half
  const int lane = tid & 63, wave = tid >> 6;
  const int q = lane >> 4, c = lane & 15;
  const int wm = wave >> 1, wn = wave & 1;

  // row stride 40 ushorts = 80 B: b128 fragment reads spread banks (2-way, free)
  __shared__ unsigned short As[128][40];  // [m][k]
  __shared__ unsigned short Bs[128][40];  // [n][k] (transposed W)

  f32x4 acc[4][4];
#pragma unroll
  for (int i = 0; i < 4; ++i)
#pragma unroll
    for (int t = 0; t < 4; ++t) acc[i][t] = (f32x4){0.f, 0.f, 0.f, 0.f};

  const int ar = tid >> 1;            // A stage row 0..127
  const int ak = (tid & 1) * 16;      // A stage k 0/16
  const int bk = tid >> 3;            // B stage k 0..31
  const int bn0 = (tid & 7) * 16;     // B stage n 0..112

  for (int k0 = 0; k0 < NODE_DIM; k0 += 32) {
    {  // A: x rows -> bf16 LDS (hw packed cvt)
      const int r = row0 + ar;
      union { short8 s; unsigned u[4]; } t0, t1;
      if (r < N_NODES) {
        const float4* src = (const float4*)&x[(size_t)r * NODE_DIM + k0 + ak];
        float4 f0 = src[0], f1 = src[1], f2 = src[2], f3 = src[3];
        t0.u[0] = f2bf_pk(f0.x, f0.y); t0.u[1] = f2bf_pk(f0.z, f0.w);
        t0.u[2] = f2bf_pk(f1.x, f1.y); t0.u[3] = f2bf_pk(f1.z, f1.w);
        t1.u[0] = f2bf_pk(f2.x, f2.y); t1.u[1] = f2bf_pk(f2.z, f2.w);
        t1.u[2] = f2bf_pk(f3.x, f3.y); t1.u[3] = f2bf_pk(f3.z, f3.w);
      } else {
        t0.u[0] = t0.u[1] = t0.u[2] = t0.u[3] = 0u;
        t1.u[0] = t1.u[1] = t1.u[2] = t1.u[3] = 0u;
      }
      *(short8*)&As[ar][ak] = t0.s;
      *(short8*)&As[ar][ak + 8] = t1.s;
    }
    {  // B: We rows -> transposed bf16 LDS
      const float4* src = (const float4*)&We[(size_t)(half * 256 + k0 + bk) * HIDDEN + ncol0 + bn0];
#pragma unroll
      for (int v = 0; v < 4; ++v) {
        float4 f = src[v];
        Bs[bn0 + v * 4 + 0][bk] = f2bf(f.x);
        Bs[bn0 + v * 4 + 1][bk] = f2bf(f.y);
        Bs[bn0 + v * 4 + 2][bk] = f2bf(f.z);
        Bs[bn0 + v * 4 + 3][bk] = f2bf(f.w);
      }
    }
    __syncthreads();
    short8 Af[4], Bf[4];
#pragma unroll
    for (int i = 0; i < 4; ++i) Af[i] = *(const short8*)&As[wm * 64 + i * 16 + c][q * 8];
#pragma unroll
    for (int t = 0; t < 4; ++t) Bf[t] = *(const short8*)&Bs[wn * 64 + t * 16 + c][q * 8];
#pragma unroll
    for (int i = 0; i < 4; ++i)
#pragma unroll
      for (int t = 0; t < 4; ++t)
        acc[i][t] = __builtin_amdgcn_mfma_f32_16x16x32_bf16(Af[i], Bf[t], acc[i][t], 0, 0, 0);
    __syncthreads();
  }

  float biasv[4] = {0.f, 0.f, 0.f, 0.f};
  const int nbase = ncol0 + wn * 64;
  if (half) {
#pragma unroll
    for (int t = 0; t < 4; ++t) biasv[t] = be[nbase + t * 16 + c];
  }
#pragma unroll
  for (int i = 0; i < 4; ++i) {
#pragma unroll
    for (int r = 0; r < 4; ++r) {
      const int node = row0 + wm * 64 + i * 16 + q * 4 + r;
      if (node < N_NODES) {
        union { ushort4 o; unsigned u[2]; } w;
        w.u[0] = f2bf_pk(acc[i][0][r] + biasv[0], acc[i][1][r] + biasv[1]);
        w.u[1] = f2bf_pk(acc[i][2][r] + biasv[2], acc[i][3][r] + biasv[3]);
        *(ushort4*)&C[(size_t)node * 512 + half * 256 + nbase + c * 4] = w.o;
      }
    }
  }
}

// ---------------- Kernel 2: MFMA fused gather + attr-GEMM + relu + mean.
// attrs read fp32, converted via hw cvt_pk. Indices prefetched one group ahead.
__global__ __launch_bounds__(256) void edge_mfma(
    const unsigned short* __restrict__ C, const int* __restrict__ ei,
    const float* __restrict__ attrs, const float* __restrict__ We,
    float* __restrict__ partial) {
  const int tid = threadIdx.x;
  const int lane = tid & 63, wave = tid >> 6;
  const int q = lane >> 4, c = lane & 15;
  const int hb = wave * 64;

  short8 Bf[4];
#pragma unroll
  for (int t = 0; t < 4; ++t) {
    short8 bf;
#pragma unroll
    for (int j = 0; j < 8; ++j) {
      int k = q * 8 + j;
      float w = (k < 16) ? We[(size_t)(512 + k) * HIDDEN + hb + t * 16 + c] : 0.0f;
      bf[j] = (short)f2bf(w);
    }
    Bf[t] = bf;
  }

  f32x4 acc4[4][4];  // [b][t]
#pragma unroll
  for (int b = 0; b < 4; ++b)
#pragma unroll
    for (int t = 0; t < 4; ++t) acc4[b][t] = (f32x4){0.f, 0.f, 0.f, 0.f};

  const f32x4 zero4 = {0.f, 0.f, 0.f, 0.f};
  const int ngroups = N_EDGES / 16;
  int g = blockIdx.x;
  int4 ns4 = make_int4(0, 0, 0, 0), nd4 = ns4;
  if (g < ngroups) {
    ns4 = *(const int4*)&ei[g * 16 + q * 4];
    nd4 = *(const int4*)&ei[N_EDGES + g * 16 + q * 4];
  }
  while (g < ngroups) {
    const int e0 = g * 16;
    const int gn = g + gridDim.x;
    int4 ns4n = ns4, nd4n = nd4;
    if (gn < ngroups) {  // prefetch next group's indices
      ns4n = *(const int4*)&ei[gn * 16 + q * 4];
      nd4n = *(const int4*)&ei[N_EDGES + gn * 16 + q * 4];
    }

    // base gather (issue before attr cvt so loads overlap VALU)
    f32x4 base4[4];  // [t], component = row r (bias folded into dst half)
    {
      const int nn[4] = {ns4.x, ns4.y, ns4.z, ns4.w};
      const int dd[4] = {nd4.x, nd4.y, nd4.z, nd4.w};
#pragma unroll
      for (int r = 0; r < 4; ++r) {
        const uint2 s = *(const uint2*)&C[(size_t)nn[r] * 512 + hb + c * 4];
        const uint2 d = *(const uint2*)&C[(size_t)dd[r] * 512 + 256 + hb + c * 4];
        base4[0][r] = __uint_as_float(s.x << 16) + __uint_as_float(d.x << 16);
        base4[1][r] = __uint_as_float(s.x & 0xFFFF0000u) + __uint_as_float(d.x & 0xFFFF0000u);
        base4[2][r] = __uint_as_float(s.y << 16) + __uint_as_float(d.y << 16);
        base4[3][r] = __uint_as_float(s.y & 0xFFFF0000u) + __uint_as_float(d.y & 0xFFFF0000u);
      }
    }

    // A fragments: fp32 attrs -> bf16 via hw cvt_pk (rows only for q<2)
    short8 Af[4];
    if (q < 2) {
#pragma unroll
      for (int b = 0; b < 4; ++b) {
        const size_t off = ((size_t)b * N_EDGES + e0 + c) * 16 + q * 8;
        const float4 a0 = *(const float4*)&attrs[off];
        const float4 a1 = *(const float4*)&attrs[off + 4];
        union { short8 s; unsigned u[4]; } af;
        af.u[0] = f2bf_pk(a0.x, a0.y); af.u[1] = f2bf_pk(a0.z, a0.w);
        af.u[2] = f2bf_pk(a1.x, a1.y); af.u[3] = f2bf_pk(a1.z, a1.w);
        Af[b] = af.s;
      }
    } else {
      short8 z;
#pragma unroll
      for (int j = 0; j < 8; ++j) z[j] = 0;
#pragma unroll
      for (int b = 0; b < 4; ++b) Af[b] = z;
    }

#pragma unroll
    for (int b = 0; b < 4; ++b) {
#pragma unroll
      for (int t = 0; t < 4; ++t) {
        f32x4 S = __builtin_amdgcn_mfma_f32_16x16x32_bf16(Af[b], Bf[t], zero4, 0, 0, 0);
        f32x4 u = S + base4[t];
        u[0] = fmaxf(u[0], 0.f); u[1] = fmaxf(u[1], 0.f);
        u[2] = fmaxf(u[2], 0.f); u[3] = fmaxf(u[3], 0.f);
        acc4[b][t] += u;
      }
    }
    ns4 = ns4n; nd4 = nd4n; g = gn;
  }

#pragma unroll
  for (int b = 0; b < 4; ++b)
#pragma unroll
    for (int t = 0; t < 4; ++t) {
      float v = acc4[b][t][0] + acc4[b][t][1] + acc4[b][t][2] + acc4[b][t][3];
      v += __shfl_xor(v, 16, 64);
      v += __shfl_xor(v, 32, 64);
      if (q == 0) atomicAdd(&partial[b * HIDDEN + hb + t * 16 + c], v);
    }
}

// ---------------- Kernel 3: out[b,o] = (S[b,:]/E) @ W_graph + b_graph
__global__ __launch_bounds__(256) void graph_out(
    const float* __restrict__ partial, const float* __restrict__ Wg,
    const float* __restrict__ bg, float* __restrict__ out) {
  const int o = blockIdx.x;    // 0..127
  const int hh = threadIdx.x;  // 0..255
  const int lane = hh & 63, wave = hh >> 6;
  const float w = Wg[(size_t)hh * OUT_DIM + o];
  float v[4];
#pragma unroll
  for (int b = 0; b < 4; ++b) v[b] = partial[b * HIDDEN + hh] * w;
#pragma unroll
  for (int off = 32; off >= 1; off >>= 1)
#pragma unroll
    for (int b = 0; b < 4; ++b) v[b] += __shfl_down(v[b], off, 64);
  __shared__ float red[4][4];
  if (lane == 0)
#pragma unroll
    for (int b = 0; b < 4; ++b) red[wave][b] = v[b];
  __syncthreads();
  if (hh < 4) {
    float s = red[0][hh] + red[1][hh] + red[2][hh] + red[3][hh];
    out[hh * OUT_DIM + o] = s * (1.0f / (float)N_EDGES) + bg[o];
  }
}

extern "C" void kernel_launch(void* const* d_in, const int* in_sizes, int n_in,
                              void* d_out, int out_size, void* d_ws, size_t ws_size,
                              hipStream_t stream) {
  const float* x  = (const float*)d_in[0];
  const int*   ei = (const int*)d_in[1];
  const float* ea = (const float*)d_in[2];
  const float* We = (const float*)d_in[3];
  const float* be = (const float*)d_in[4];
  const float* Wg = (const float*)d_in[5];
  const float* bg = (const float*)d_in[6];
  float* out = (float*)d_out;

  unsigned short* C = (unsigned short*)d_ws;                 // 20000*512 bf16 = 20.48 MB
  float* partial = (float*)((char*)d_ws + (size_t)N_NODES * 512 * 2);

  proj_mfma<<<PROJ_BLOCKS, 256, 0, stream>>>(x, We, be, C, partial);
  edge_mfma<<<2500, 256, 0, stream>>>(C, ei, ea, We, partial);
  graph_out<<<128, 256, 0, stream>>>(partial, Wg, bg, out);
}

// Round 8
// 290.594 us; speedup vs baseline: 1.0066x; 1.0024x over previous
//
#include <hip/hip_runtime.h>
#include <hip/hip_bf16.h>

#define N_NODES 20000
#define N_EDGES 400000
#define NODE_DIM 256
#define HIDDEN 256
#define OUT_DIM 128

typedef __attribute__((ext_vector_type(8))) short short8;
typedef __attribute__((ext_vector_type(4))) float f32x4;

// hardware v_cvt_pk_bf16_f32 (RNE), 2 floats -> packed 2 bf16
__device__ inline unsigned f2bf_pk(float a, float b) {
  __hip_bfloat162 h = __float22bfloat162_rn(float2{a, b});
  union { __hip_bfloat162 h; unsigned u; } v;
  v.h = h;
  return v.u;
}
__device__ inline unsigned short f2bf(float f) {
  union { float f; unsigned u; } v; v.f = f;
  unsigned r = (v.u + 0x7FFFu + ((v.u >> 16) & 1u)) >> 16;
  return (unsigned short)r;
}

// ---------------- Kernel 0: prep — attrs fp32->bf16, Wt transpose->bf16, zero partial.
// Wt[n*256+k] = W_src[k][n] (n<256) or W_dst[k][n-256] (n>=256), bf16.
template <bool CONV_ATTRS>
__global__ __launch_bounds__(256) void prep(
    const float* __restrict__ attrs, unsigned short* __restrict__ attrs_bf,
    const float* __restrict__ We, unsigned short* __restrict__ Wt,
    float* __restrict__ partial) {
  const int tid = blockIdx.x * 256 + threadIdx.x;
  if (blockIdx.x == 0) {
    for (int i = threadIdx.x; i < 4 * HIDDEN; i += 256) partial[i] = 0.f;
  }
  if (tid < 512 * 256) {  // Wt build (one-time transpose, tiny: 0.5 MB read)
    const int n = tid >> 8, k = tid & 255;
    const float w = (n < 256) ? We[(size_t)k * 256 + n]
                              : We[(size_t)(256 + k) * 256 + (n - 256)];
    Wt[tid] = f2bf(w);
  }
  if (CONV_ATTRS) {
    const int nt = gridDim.x * 256;
    const int total4 = 4 * N_EDGES * 16 / 4;  // float4 granules
    for (int i = tid; i < total4; i += nt) {
      float4 v = ((const float4*)attrs)[i];
      union { ushort4 o; unsigned u[2]; } w;
      w.u[0] = f2bf_pk(v.x, v.y);
      w.u[1] = f2bf_pk(v.z, v.w);
      ((ushort4*)attrs_bf)[i] = w.o;
    }
  }
}

// ---------------- Kernel 1: bf16 MFMA proj GEMM (all-b128 staging).
// C layout (bf16): C[node][half*256 + nbase + c*4 + t], h = nbase + t*16 + c.
// half 0 = x@W_src, half 1 = x@W_dst + b_edge (bias folded in epilogue).
__global__ __launch_bounds__(256) void proj_mfma(
    const float* __restrict__ x, const unsigned short* __restrict__ Wt,
    const float* __restrict__ be, unsigned short* __restrict__ C) {
  const int tid = threadIdx.x;
  const int bm = blockIdx.x >> 2;
  const int bnb = blockIdx.x & 3;
  const int row0 = bm * 128;
  const int col0 = bnb * 128;         // 0,128,256,384
  const int half = col0 >> 8;
  const int lane = tid & 63, wave = tid >> 6;
  const int q = lane >> 4, c = lane & 15;
  const int wm = wave >> 1, wn = wave & 1;

  // row stride 40 ushorts = 80 B: fragment b128 reads spread banks
  __shared__ unsigned short As[128][40];  // [m][k]
  __shared__ unsigned short Bs[128][40];  // [n][k]

  f32x4 acc[4][4];
#pragma unroll
  for (int i = 0; i < 4; ++i)
#pragma unroll
    for (int t = 0; t < 4; ++t) acc[i][t] = (f32x4){0.f, 0.f, 0.f, 0.f};

  const int sr = tid >> 1;            // stage row 0..127 (A and B)
  const int sk = (tid & 1) * 16;      // stage k 0/16

  for (int k0 = 0; k0 < NODE_DIM; k0 += 32) {
    {  // A: x fp32 -> bf16 LDS via hw pk cvt (4 float4 loads, 8 cvt, 2 b128 writes)
      const int r = row0 + sr;
      union { short8 s; unsigned u[4]; } t0, t1;
      if (r < N_NODES) {
        const float4* src = (const float4*)&x[(size_t)r * NODE_DIM + k0 + sk];
        float4 f0 = src[0], f1 = src[1], f2 = src[2], f3 = src[3];
        t0.u[0] = f2bf_pk(f0.x, f0.y); t0.u[1] = f2bf_pk(f0.z, f0.w);
        t0.u[2] = f2bf_pk(f1.x, f1.y); t0.u[3] = f2bf_pk(f1.z, f1.w);
        t1.u[0] = f2bf_pk(f2.x, f2.y); t1.u[1] = f2bf_pk(f2.z, f2.w);
        t1.u[2] = f2bf_pk(f3.x, f3.y); t1.u[3] = f2bf_pk(f3.z, f3.w);
      } else {
        t0.u[0] = t0.u[1] = t0.u[2] = t0.u[3] = 0u;
        t1.u[0] = t1.u[1] = t1.u[2] = t1.u[3] = 0u;
      }
      *(short8*)&As[sr][sk] = t0.s;
      *(short8*)&As[sr][sk + 8] = t1.s;
    }
    {  // B: pure bf16 copy from pre-transposed Wt (2 short8 loads, 2 b128 writes)
      const unsigned short* src = &Wt[(size_t)(col0 + sr) * 256 + k0 + sk];
      *(short8*)&Bs[sr][sk] = *(const short8*)src;
      *(short8*)&Bs[sr][sk + 8] = *(const short8*)(src + 8);
    }
    __syncthreads();
    short8 Af[4], Bf[4];
#pragma unroll
    for (int i = 0; i < 4; ++i) Af[i] = *(const short8*)&As[wm * 64 + i * 16 + c][q * 8];
#pragma unroll
    for (int t = 0; t < 4; ++t) Bf[t] = *(const short8*)&Bs[wn * 64 + t * 16 + c][q * 8];
#pragma unroll
    for (int i = 0; i < 4; ++i)
#pragma unroll
      for (int t = 0; t < 4; ++t)
        acc[i][t] = __builtin_amdgcn_mfma_f32_16x16x32_bf16(Af[i], Bf[t], acc[i][t], 0, 0, 0);
    __syncthreads();
  }

  float biasv[4] = {0.f, 0.f, 0.f, 0.f};
  const int nbase = (col0 & 255) + wn * 64;
  if (half) {
#pragma unroll
    for (int t = 0; t < 4; ++t) biasv[t] = be[nbase + t * 16 + c];
  }
#pragma unroll
  for (int i = 0; i < 4; ++i) {
#pragma unroll
    for (int r = 0; r < 4; ++r) {
      const int node = row0 + wm * 64 + i * 16 + q * 4 + r;
      if (node < N_NODES) {
        union { ushort4 o; unsigned u[2]; } w;
        w.u[0] = f2bf_pk(acc[i][0][r] + biasv[0], acc[i][1][r] + biasv[1]);
        w.u[1] = f2bf_pk(acc[i][2][r] + biasv[2], acc[i][3][r] + biasv[3]);
        *(ushort4*)&C[(size_t)node * 512 + half * 256 + nbase + c * 4] = w.o;
      }
    }
  }
}

// ---------------- Kernel 2: MFMA fused gather + attr-GEMM + relu + mean (R5 structure).
template <bool PRE>
__global__ __launch_bounds__(256) void edge_mfma(
    const unsigned short* __restrict__ C, const int* __restrict__ ei,
    const float* __restrict__ attrs_f, const unsigned short* __restrict__ attrs_b,
    const float* __restrict__ We, float* __restrict__ partial) {
  const int tid = threadIdx.x;
  const int lane = tid & 63, wave = tid >> 6;
  const int q = lane >> 4, c = lane & 15;
  const int hb = wave * 64;

  short8 Bf[4];
#pragma unroll
  for (int t = 0; t < 4; ++t) {
    short8 bf;
#pragma unroll
    for (int j = 0; j < 8; ++j) {
      int k = q * 8 + j;
      float w = (k < 16) ? We[(size_t)(512 + k) * HIDDEN + hb + t * 16 + c] : 0.0f;
      bf[j] = (short)f2bf(w);
    }
    Bf[t] = bf;
  }

  f32x4 acc4[4][4];  // [b][t]
#pragma unroll
  for (int b = 0; b < 4; ++b)
#pragma unroll
    for (int t = 0; t < 4; ++t) acc4[b][t] = (f32x4){0.f, 0.f, 0.f, 0.f};

  const f32x4 zero4 = {0.f, 0.f, 0.f, 0.f};
  const int ngroups = N_EDGES / 16;
  for (int g = blockIdx.x; g < ngroups; g += gridDim.x) {
    const int e0 = g * 16;
    const int4 ns4 = *(const int4*)&ei[e0 + q * 4];
    const int4 nd4 = *(const int4*)&ei[N_EDGES + e0 + q * 4];

    short8 Af[4];
    if (q < 2) {
      if (PRE) {
#pragma unroll
        for (int b = 0; b < 4; ++b)
          Af[b] = *(const short8*)&attrs_b[((size_t)b * N_EDGES + e0 + c) * 16 + q * 8];
      } else {
#pragma unroll
        for (int b = 0; b < 4; ++b) {
          const size_t off = ((size_t)b * N_EDGES + e0 + c) * 16 + q * 8;
          const float4 a0 = *(const float4*)&attrs_f[off];
          const float4 a1 = *(const float4*)&attrs_f[off + 4];
          union { short8 s; unsigned u[4]; } af;
          af.u[0] = f2bf_pk(a0.x, a0.y); af.u[1] = f2bf_pk(a0.z, a0.w);
          af.u[2] = f2bf_pk(a1.x, a1.y); af.u[3] = f2bf_pk(a1.z, a1.w);
          Af[b] = af.s;
        }
      }
    } else {
      short8 z;
#pragma unroll
      for (int j = 0; j < 8; ++j) z[j] = 0;
#pragma unroll
      for (int b = 0; b < 4; ++b) Af[b] = z;
    }

    f32x4 base4[4];  // [t], component = row r (bias folded into dst half)
    {
      const int nn[4] = {ns4.x, ns4.y, ns4.z, ns4.w};
      const int dd[4] = {nd4.x, nd4.y, nd4.z, nd4.w};
#pragma unroll
      for (int r = 0; r < 4; ++r) {
        const uint2 s = *(const uint2*)&C[(size_t)nn[r] * 512 + hb + c * 4];
        const uint2 d = *(const uint2*)&C[(size_t)dd[r] * 512 + 256 + hb + c * 4];
        base4[0][r] = __uint_as_float(s.x << 16) + __uint_as_float(d.x << 16);
        base4[1][r] = __uint_as_float(s.x & 0xFFFF0000u) + __uint_as_float(d.x & 0xFFFF0000u);
        base4[2][r] = __uint_as_float(s.y << 16) + __uint_as_float(d.y << 16);
        base4[3][r] = __uint_as_float(s.y & 0xFFFF0000u) + __uint_as_float(d.y & 0xFFFF0000u);
      }
    }

#pragma unroll
    for (int b = 0; b < 4; ++b) {
#pragma unroll
      for (int t = 0; t < 4; ++t) {
        f32x4 S = __builtin_amdgcn_mfma_f32_16x16x32_bf16(Af[b], Bf[t], zero4, 0, 0, 0);
        f32x4 u = S + base4[t];
        u[0] = fmaxf(u[0], 0.f); u[1] = fmaxf(u[1], 0.f);
        u[2] = fmaxf(u[2], 0.f); u[3] = fmaxf(u[3], 0.f);
        acc4[b][t] += u;
      }
    }
  }

#pragma unroll
  for (int b = 0; b < 4; ++b)
#pragma unroll
    for (int t = 0; t < 4; ++t) {
      float v = acc4[b][t][0] + acc4[b][t][1] + acc4[b][t][2] + acc4[b][t][3];
      v += __shfl_xor(v, 16, 64);
      v += __shfl_xor(v, 32, 64);
      if (q == 0) atomicAdd(&partial[b * HIDDEN + hb + t * 16 + c], v);
    }
}

// ---------------- Kernel 3: out[b,o] = (S[b,:]/E) @ W_graph + b_graph
__global__ __launch_bounds__(256) void graph_out(
    const float* __restrict__ partial, const float* __restrict__ Wg,
    const float* __restrict__ bg, float* __restrict__ out) {
  const int o = blockIdx.x;    // 0..127
  const int hh = threadIdx.x;  // 0..255
  const int lane = hh & 63, wave = hh >> 6;
  const float w = Wg[(size_t)hh * OUT_DIM + o];
  float v[4];
#pragma unroll
  for (int b = 0; b < 4; ++b) v[b] = partial[b * HIDDEN + hh] * w;
#pragma unroll
  for (int off = 32; off >= 1; off >>= 1)
#pragma unroll
    for (int b = 0; b < 4; ++b) v[b] += __shfl_down(v[b], off, 64);
  __shared__ float red[4][4];
  if (lane == 0)
#pragma unroll
    for (int b = 0; b < 4; ++b) red[wave][b] = v[b];
  __syncthreads();
  if (hh < 4) {
    float s = red[0][hh] + red[1][hh] + red[2][hh] + red[3][hh];
    out[hh * OUT_DIM + o] = s * (1.0f / (float)N_EDGES) + bg[o];
  }
}

extern "C" void kernel_launch(void* const* d_in, const int* in_sizes, int n_in,
                              void* d_out, int out_size, void* d_ws, size_t ws_size,
                              hipStream_t stream) {
  const float* x  = (const float*)d_in[0];
  const int*   ei = (const int*)d_in[1];
  const float* ea = (const float*)d_in[2];
  const float* We = (const float*)d_in[3];
  const float* be = (const float*)d_in[4];
  const float* Wg = (const float*)d_in[5];
  const float* bg = (const float*)d_in[6];
  float* out = (float*)d_out;

  // ws layout: C | Wt | partial | attrs_bf(optional)
  const size_t C_bytes  = (size_t)N_NODES * 512 * 2;   // 20.48 MB
  const size_t Wt_bytes = (size_t)512 * 256 * 2;       // 0.26 MB
  const size_t P_bytes  = 4 * HIDDEN * sizeof(float);  // 4 KB
  const size_t A_bytes  = (size_t)4 * N_EDGES * 16 * 2;// 51.2 MB
  unsigned short* C  = (unsigned short*)d_ws;
  unsigned short* Wt = (unsigned short*)((char*)d_ws + C_bytes);
  float* partial     = (float*)((char*)d_ws + C_bytes + Wt_bytes);
  const bool pre = ws_size >= C_bytes + Wt_bytes + P_bytes + A_bytes;
  unsigned short* attrs_bf =
      pre ? (unsigned short*)((char*)d_ws + C_bytes + Wt_bytes + P_bytes) : nullptr;

  if (pre)
    prep<true><<<1024, 256, 0, stream>>>(ea, attrs_bf, We, Wt, partial);
  else
    prep<false><<<512, 256, 0, stream>>>(ea, nullptr, We, Wt, partial);
  proj_mfma<<<157 * 4, 256, 0, stream>>>(x, Wt, be, C);
  if (pre)
    edge_mfma<true><<<2500, 256, 0, stream>>>(C, ei, nullptr, attrs_bf, We, partial);
  else
    edge_mfma<false><<<2500, 256, 0, stream>>>(C, ei, ea, nullptr, We, partial);
  graph_out<<<128, 256, 0, stream>>>(partial, Wg, bg, out);
}